// Round 1
// 1008.097 us; speedup vs baseline: 1.1466x; 1.1466x over previous
//
#include <hip/hip_runtime.h>

#define T_STEPS 2048
#define BATCH   128
#define HID     100     // LSTM hidden size
#define HP      112     // padded hidden length (multiple of 16)
#define NTH     448     // 7 waves of 64

#define LOG2E 1.44269504088896340736f

// DPP quad_perm helpers (VALU pipe, immediate ctrl)
template <int CTRL>
__device__ __forceinline__ float dpp_mov(float v) {
    int y = __builtin_amdgcn_update_dpp(0, __float_as_int(v), CTRL, 0xF, 0xF, true);
    return __int_as_float(y);
}

__global__ __launch_bounds__(NTH)
__attribute__((amdgpu_waves_per_eu(1)))   // min-only: full VGPR budget so the
                                          // ~120 loop-carried weights fit in ARCH vgprs
void lstm_caviar_kernel(
    const float* __restrict__ x,      // [T, B, 1]
    const float* __restrict__ W_ih,   // [400, 1]
    const float* __restrict__ W_hh,   // [400, 100]
    const float* __restrict__ b_ih,   // [400]
    const float* __restrict__ b_hh,   // [400]
    const float* __restrict__ W1,     // [64, 100]
    const float* __restrict__ b1,     // [64]
    const float* __restrict__ W2,     // [1, 64]
    const float* __restrict__ b2,     // [1]
    float* __restrict__ out)          // [1]
{
    __shared__ __align__(16) float h_buf[2][HP];
    __shared__ float x_lds[T_STEPS];
    __shared__ float red_lds[64];

    const int tid = threadIdx.x;
    const int j   = tid >> 2;     // hidden unit owned by this quad
    const int s   = tid & 3;      // k-split / gate-specialization lane
    const bool active = (j < HID);

    // stage batch-0 inputs (x[t,0,0] = flat[t*BATCH]) into LDS once
    for (int t = tid; t < T_STEPS; t += NTH)
        x_lds[t] = x[t * BATCH];
    if (tid < HP) { h_buf[0][tid] = 0.0f; h_buf[1][tid] = 0.0f; }

    // Preload W_hh fragments: lane covers k = 16*m + 4*s + d, m=0..6, d=0..3.
    // wi/bias pre-scaled by 0.25 so the 4-lane reduce sums them to exactly 1x.
    // All gate rows additionally pre-scaled by log2(e) (2*log2(e) for gate g)
    // so activations can use v_exp_f32 (exp2) with no per-step scaling mul:
    //   sigmoid(p) = rcp(1 + exp2(-L*p)),  tanh(p) = 2*rcp(1 + exp2(-2L*p)) - 1
    float w[4][28];
    float wi4[4], bs4[4];
    #pragma unroll
    for (int g = 0; g < 4; ++g) {
        const int gate = g * HID + (active ? j : 0);
        const float Lg = (g == 2) ? (2.0f * LOG2E) : LOG2E;
        const float* row = W_hh + gate * HID;
        #pragma unroll
        for (int m = 0; m < 7; ++m) {
            #pragma unroll
            for (int d = 0; d < 4; ++d) {
                const int k = 16 * m + 4 * s + d;
                w[g][m * 4 + d] = (active && k < HID) ? Lg * row[k] : 0.0f;
            }
        }
        wi4[g] = active ? 0.25f * Lg * W_ih[gate] : 0.0f;
        bs4[g] = active ? 0.25f * Lg * (b_ih[gate] + b_hh[gate]) : 0.0f;
    }

    const bool b0   = (s & 1) != 0;
    const bool b1h  = (s & 2) != 0;
    const bool is_g = (s == 2);
    float c = 0.0f;
    __syncthreads();

    for (int t = 0; t < T_STEPS; ++t) {
        const float* hb = h_buf[t & 1];
        const float xt = x_lds[t];

        float acc0 = fmaf(wi4[0], xt, bs4[0]);
        float acc1 = fmaf(wi4[1], xt, bs4[1]);
        float acc2 = fmaf(wi4[2], xt, bs4[2]);
        float acc3 = fmaf(wi4[3], xt, bs4[3]);

        #pragma unroll
        for (int m = 0; m < 7; ++m) {
            const float4 hv = *(const float4*)(hb + 16 * m + 4 * s);
            acc0 = fmaf(w[0][m*4+0], hv.x, acc0);
            acc0 = fmaf(w[0][m*4+1], hv.y, acc0);
            acc0 = fmaf(w[0][m*4+2], hv.z, acc0);
            acc0 = fmaf(w[0][m*4+3], hv.w, acc0);
            acc1 = fmaf(w[1][m*4+0], hv.x, acc1);
            acc1 = fmaf(w[1][m*4+1], hv.y, acc1);
            acc1 = fmaf(w[1][m*4+2], hv.z, acc1);
            acc1 = fmaf(w[1][m*4+3], hv.w, acc1);
            acc2 = fmaf(w[2][m*4+0], hv.x, acc2);
            acc2 = fmaf(w[2][m*4+1], hv.y, acc2);
            acc2 = fmaf(w[2][m*4+2], hv.z, acc2);
            acc2 = fmaf(w[2][m*4+3], hv.w, acc2);
            acc3 = fmaf(w[3][m*4+0], hv.x, acc3);
            acc3 = fmaf(w[3][m*4+1], hv.y, acc3);
            acc3 = fmaf(w[3][m*4+2], hv.z, acc3);
            acc3 = fmaf(w[3][m*4+3], hv.w, acc3);
        }

        // Select-then-butterfly transpose-reduce: lane s ends with the FULL
        // sum of gate s (12 VALU ops vs 19 for 4 full butterflies + select).
        // stage 1 (xor 1): a01-type partials over lane pairs
        float p01  = b0 ? acc1 : acc0;
        float p01s = b0 ? acc0 : acc1;
        float p23  = b0 ? acc3 : acc2;
        float p23s = b0 ? acc2 : acc3;
        p01 += dpp_mov<0xB1>(p01s);
        p23 += dpp_mov<0xB1>(p23s);
        // stage 2 (xor 2)
        float q  = b1h ? p23 : p01;
        float qs = b1h ? p01 : p23;
        const float tot = q + dpp_mov<0x4E>(qs);

        // lane s activates gate s (i,f,o: sigmoid; g: tanh), exp2+rcp only —
        // the log2e scaling is baked into the weights.
        const float e   = __builtin_amdgcn_exp2f(-tot);
        const float r   = __builtin_amdgcn_rcpf(1.0f + e);
        const float act = is_g ? fmaf(2.0f, r, -1.0f) : r;

        // redistribute the four activations within the quad (DPP broadcasts)
        const float ig = dpp_mov<0x00>(act);
        const float fg = dpp_mov<0x55>(act);
        const float gg = dpp_mov<0xAA>(act);
        const float og = dpp_mov<0xFF>(act);

        c = fmaf(fg, c, ig * gg);
        const float e2 = __builtin_amdgcn_exp2f(-2.0f * LOG2E * c);
        const float r2 = __builtin_amdgcn_rcpf(1.0f + e2);
        const float h  = og * fmaf(2.0f, r2, -1.0f);

        if (active && s == 0)
            h_buf[(t + 1) & 1][j] = h;
        __syncthreads();
    }

    // head: lin = W1 @ h + b1 (64), out = W2 @ lin + b2 (scalar)
    if (tid < 64) {
        const float* rw = W1 + tid * HID;
        const float* hf = h_buf[0];   // T even -> final h in buf 0
        float a = 0.0f;
        for (int k = 0; k < HID; ++k)
            a = fmaf(rw[k], hf[k], a);
        red_lds[tid] = a + b1[tid];
    }
    __syncthreads();
    if (tid == 0) {
        float a = b2[0];
        for (int k = 0; k < 64; ++k)
            a = fmaf(W2[k], red_lds[k], a);
        out[0] = a;
    }
}

extern "C" void kernel_launch(void* const* d_in, const int* in_sizes, int n_in,
                              void* d_out, int out_size, void* d_ws, size_t ws_size,
                              hipStream_t stream) {
    lstm_caviar_kernel<<<1, NTH, 0, stream>>>(
        (const float*)d_in[0],  // input_seq
        (const float*)d_in[1],  // W_ih
        (const float*)d_in[2],  // W_hh
        (const float*)d_in[3],  // b_ih
        (const float*)d_in[4],  // b_hh
        (const float*)d_in[5],  // W1
        (const float*)d_in[6],  // b1
        (const float*)d_in[7],  // W2
        (const float*)d_in[8],  // b2
        (float*)d_out);
}